// Round 9
// baseline (151.984 us; speedup 1.0000x reference)
//
#include <hip/hip_runtime.h>
#include <hip/hip_bf16.h>

// TripletLoss, N=8192, D=256 fp32, targets in [0,128).
// out[0]=mean(relu(dist_ap-dist_an+0.3)), out[1]=mean(dist_an>dist_ap)
// dist=sqrt(clip(si+sj-2dot,1e-12)); clip/sqrt deferred (monotone).
// Reductions in KEY SPACE: key = B + s_other - 2dot (B=65536 keeps keys
// positive -> uint order == float order for atomicMax/Min).
//
// R8: (a) finish fused into tile_slow via arrival counter, NO __threadfence
// (all cross-block state is device-scope atomics = coherent point; the
// __syncthreads vmcnt-drain orders them before the ticket add). R5 lesson:
// per-block fences wipe per-XCD L2 (buffer_wbl2+inv) -> never in hot path.
// (b) BK=64 double-buffer: 4 barriers/block instead of 8 (each vmcnt(0)
// drain now sits a 2x-longer compute phase after its DMA issue), at the
// cost of 66KB LDS -> 2 blocks/CU (was 3). m132 warns; counters attribute.
// Split fast/slow kernels kept (R7: register-union costs a wave/SIMD).

#define N 8192
#define D 256
#define MARGIN 0.3f
#define NBLK 2080   // 64*65/2 lower-triangle 128x128 tiles
#define BIAS 65536.0f

typedef __bf16  bf16x8  __attribute__((ext_vector_type(8)));
typedef float   floatx4 __attribute__((ext_vector_type(4)));

__device__ __forceinline__ void load_lds16(const void* g, void* s) {
  __builtin_amdgcn_global_load_lds(
      (const __attribute__((address_space(1))) void*)g,
      (__attribute__((address_space(3))) void*)s, 16, 0, 0);
}

__device__ __forceinline__ void tri_decode(int bi, int& by, int& bx) {
  by = (int)((sqrtf(8.0f * (float)bi + 1.0f) - 1.0f) * 0.5f);
  while ((by + 1) * (by + 2) / 2 <= bi) ++by;
  while (by * (by + 1) / 2 > bi) --by;
  bx = bi - by * (by + 1) / 2;
}

// ---- Kernel A: rank-sort by class + bf16 cast + biased sq-norms + init ------
__global__ __launch_bounds__(256) void prep_kernel(
    const float* __restrict__ X, const int* __restrict__ tgt,
    unsigned short* __restrict__ Xb, float* __restrict__ sqB,
    int* __restrict__ tgtP, unsigned* __restrict__ pmax, unsigned* __restrict__ nmin,
    unsigned* __restrict__ counter) {
  __shared__ int keys[N];  // 32 KB: key = cls*16384 + j (lexicographic rank)
  const int t = threadIdx.x;
  const int lane = t & 63, wave = t >> 6;
  if (blockIdx.x == 0 && t == 0) *counter = 0u;
#pragma unroll
  for (int u = 0; u < 32; ++u) {
    int j = u * 256 + t;
    keys[j] = tgt[j] * 16384 + j;
  }
  __syncthreads();
  const int row0 = blockIdx.x * 8 + wave * 2;
#pragma unroll
  for (int r = 0; r < 2; ++r) {
    const int row = row0 + r;
    const int Ki = keys[row];
    int cnt = 0;
#pragma unroll 4
    for (int u = 0; u < 32; ++u) {
      int4 k4 = *reinterpret_cast<const int4*>(&keys[u * 256 + lane * 4]);
      cnt += (k4.x < Ki) + (k4.y < Ki) + (k4.z < Ki) + (k4.w < Ki);
    }
#pragma unroll
    for (int o = 1; o < 64; o <<= 1) cnt += __shfl_xor(cnt, o);
    // cnt == sorted position (uniform across lanes)
    float4 v = *reinterpret_cast<const float4*>(X + (size_t)row * D + lane * 4);
    ushort4 h;
    {
      __hip_bfloat16 b0 = __float2bfloat16(v.x), b1 = __float2bfloat16(v.y);
      __hip_bfloat16 b2 = __float2bfloat16(v.z), b3 = __float2bfloat16(v.w);
      h.x = *reinterpret_cast<unsigned short*>(&b0);
      h.y = *reinterpret_cast<unsigned short*>(&b1);
      h.z = *reinterpret_cast<unsigned short*>(&b2);
      h.w = *reinterpret_cast<unsigned short*>(&b3);
    }
    *reinterpret_cast<ushort4*>(Xb + (size_t)cnt * D + lane * 4) = h;
    float s = v.x * v.x + v.y * v.y + v.z * v.z + v.w * v.w;
#pragma unroll
    for (int o = 32; o > 0; o >>= 1) s += __shfl_down(s, o);
    if (lane == 0) {
      sqB[cnt]  = s + BIAS;
      tgtP[cnt] = Ki >> 14;
      pmax[row] = 0u;            // identity for max of positive keys
      nmin[row] = 0x7F800000u;   // +inf
    }
  }
}

// ---- Kernel B1: FAST tiles (no same-class pairs) — maskless min only --------
__global__ __launch_bounds__(256) void tile_fast(
    const unsigned short* __restrict__ Xb, const float* __restrict__ sqB,
    const int* __restrict__ tgtP, unsigned* __restrict__ nmin) {
  int by, bx; tri_decode(blockIdx.x, by, bx);
  const int rowBase = by * 128, colBase = bx * 128;
  if (tgtP[rowBase + 127] >= tgtP[colBase] && tgtP[colBase + 127] >= tgtP[rowBase])
    return;  // overlap -> slow kernel

  const int t = threadIdx.x;
  const int lane = t & 63, wave = t >> 6;
  const int wy = wave >> 1, wx = wave & 1;
  const int quad = lane >> 4, l15 = lane & 15;

  // 4 slices each for A/B: [buf(2)][slice(2)][128x32], XOR-swizzled chunks
  __shared__ __align__(16) unsigned short As[4 * 128 * 32];  // 32 KB
  __shared__ __align__(16) unsigned short Bs[4 * 128 * 32];  // 32 KB
  __shared__ float sqr[128], sqc[128];
  __shared__ unsigned nmL[128], nmLc[128];

  if (t < 128) { sqr[t] = sqB[rowBase + t]; nmL[t] = 0x7F800000u; }
  else { int u = t - 128; sqc[u] = sqB[colBase + u]; nmLc[u] = 0x7F800000u; }

  const unsigned short* Ag = Xb + (size_t)rowBase * D;
  const unsigned short* Bg = Xb + (size_t)colBase * D;

  int goff[2], lbase[2];
#pragma unroll
  for (int it = 0; it < 2; ++it) {
    int p = t + it * 256;
    int row = p >> 2;
    int c = (p & 3) ^ (row & 3);
    goff[it] = row * D + c * 8;
    lbase[it] = (it * 256 + wave * 64) * 16;
  }
  int aAddr[4], bAddr[4];
#pragma unroll
  for (int mi = 0; mi < 4; ++mi) {
    int row = wy * 64 + mi * 16 + l15;
    aAddr[mi] = (row * 4 + (quad ^ (row & 3))) * 16;
  }
#pragma unroll
  for (int nj = 0; nj < 4; ++nj) {
    int col = wx * 64 + nj * 16 + l15;
    bAddr[nj] = (col * 4 + (quad ^ (col & 3))) * 16;
  }

  // stage mega-iter m (2 slices of K=32) into buffer buf
#define STAGE(m, buf)                                                        \
  {                                                                          \
    _Pragma("unroll")                                                        \
    for (int s = 0; s < 2; ++s) {                                            \
      int k0 = ((m) * 2 + s) * 32;                                           \
      char* ab = (char*)As + ((buf) * 2 + s) * 8192;                         \
      char* bb = (char*)Bs + ((buf) * 2 + s) * 8192;                         \
      _Pragma("unroll")                                                      \
      for (int it = 0; it < 2; ++it) {                                       \
        load_lds16(Ag + goff[it] + k0, ab + lbase[it]);                      \
        load_lds16(Bg + goff[it] + k0, bb + lbase[it]);                      \
      }                                                                      \
    }                                                                        \
  }

  STAGE(0, 0);

  floatx4 acc[4][4];
#pragma unroll
  for (int mi = 0; mi < 4; ++mi)
#pragma unroll
    for (int nj = 0; nj < 4; ++nj)
      acc[mi][nj] = (floatx4){0.f, 0.f, 0.f, 0.f};

#pragma unroll
  for (int m = 0; m < 4; ++m) {
    __syncthreads();  // drains buf[m&1]'s DMA (issued one mega-phase ago)
    if (m < 3) STAGE(m + 1, (m + 1) & 1);
#pragma unroll
    for (int s = 0; s < 2; ++s) {
      const char* ab = (const char*)As + ((m & 1) * 2 + s) * 8192;
      const char* bb = (const char*)Bs + ((m & 1) * 2 + s) * 8192;
      bf16x8 a[4], b[4];
#pragma unroll
      for (int mi = 0; mi < 4; ++mi)
        a[mi] = *reinterpret_cast<const bf16x8*>(ab + aAddr[mi]);
#pragma unroll
      for (int nj = 0; nj < 4; ++nj)
        b[nj] = *reinterpret_cast<const bf16x8*>(bb + bAddr[nj]);
#pragma unroll
      for (int mi = 0; mi < 4; ++mi)
#pragma unroll
        for (int nj = 0; nj < 4; ++nj)
          acc[mi][nj] = __builtin_amdgcn_mfma_f32_16x16x32_bf16(a[mi], b[nj], acc[mi][nj], 0, 0, 0);
    }
  }

  // maskless epilogue: rowkey = sqB_col - 2dot (-> nmL), colkey = sqB_row - 2dot
  float sqcB_l[4];
#pragma unroll
  for (int nj = 0; nj < 4; ++nj) sqcB_l[nj] = sqc[wx * 64 + nj * 16 + l15];

  float nm[16], cmN[4];
#pragma unroll
  for (int s = 0; s < 16; ++s) nm[s] = __builtin_huge_valf();
#pragma unroll
  for (int nj = 0; nj < 4; ++nj) cmN[nj] = __builtin_huge_valf();

#pragma unroll
  for (int mi = 0; mi < 4; ++mi) {
    floatx4 siB4 = *reinterpret_cast<const floatx4*>(&sqr[wy * 64 + mi * 16 + quad * 4]);
#pragma unroll
    for (int r = 0; r < 4; ++r) {
      float siB = siB4[r];
      int s = mi * 4 + r;
#pragma unroll
      for (int nj = 0; nj < 4; ++nj) {
        float dot = acc[mi][nj][r];
        nm[s]   = fminf(nm[s],   fmaf(-2.f, dot, sqcB_l[nj]));
        cmN[nj] = fminf(cmN[nj], fmaf(-2.f, dot, siB));
      }
    }
  }

#pragma unroll
  for (int m = 8; m >= 1; m >>= 1) {
#pragma unroll
    for (int j = 0; j < m; ++j) {
      bool up = (l15 & m) != 0;
      float sn = up ? nm[j] : nm[j + m];
      float rn = __shfl_xor(sn, m);
      float kn = up ? nm[j + m] : nm[j];
      nm[j] = fminf(kn, rn);
    }
  }
  {
    int rowIdx = wy * 64 + ((l15 >> 2) << 4) + (quad << 2) + (l15 & 3);
    atomicMin(&nmL[rowIdx], __float_as_uint(nm[0]));
  }
#pragma unroll
  for (int nj = 0; nj < 4; ++nj) {
    cmN[nj] = fminf(cmN[nj], __shfl_xor(cmN[nj], 16));
    cmN[nj] = fminf(cmN[nj], __shfl_xor(cmN[nj], 32));
  }
  {
    float vN = (quad == 0) ? cmN[0] : (quad == 1) ? cmN[1] : (quad == 2) ? cmN[2] : cmN[3];
    atomicMin(&nmLc[wx * 64 + quad * 16 + l15], __float_as_uint(vN));
  }
  __syncthreads();

  if (t < 128) atomicMin(&nmin[rowBase + t], nmL[t]);
  else { int u = t - 128; atomicMin(&nmin[colBase + u], nmLc[u]); }
}

// ---- Kernel B2: SLOW tiles (class overlap) + fused last-block finish --------
__global__ __launch_bounds__(256) void tile_slow(
    const unsigned short* __restrict__ Xb, const float* __restrict__ sqB,
    const int* __restrict__ tgtP, unsigned* __restrict__ pmax, unsigned* __restrict__ nmin,
    unsigned* __restrict__ counter, float* __restrict__ out) {
  int by, bx; tri_decode(blockIdx.x, by, bx);
  const int rowBase = by * 128, colBase = bx * 128;
  const int t = threadIdx.x;
  const int lane = t & 63, wave = t >> 6;

  __shared__ unsigned ticketS;
  __shared__ float ls[4], ps[4];

  const bool active =
      (tgtP[rowBase + 127] >= tgtP[colBase] && tgtP[colBase + 127] >= tgtP[rowBase]);

  if (active) {
    const int wy = wave >> 1, wx = wave & 1;
    const int quad = lane >> 4, l15 = lane & 15;

    __shared__ __align__(16) unsigned short As[4 * 128 * 32];
    __shared__ __align__(16) unsigned short Bs[4 * 128 * 32];
    __shared__ float sqr[128], sqc[128];
    __shared__ int   tr[128], tc[128];
    __shared__ unsigned pmL[128], nmL[128], pmLc[128], nmLc[128];

    if (t < 128) {
      sqr[t] = sqB[rowBase + t]; tr[t] = tgtP[rowBase + t];
      pmL[t] = 0u; nmL[t] = 0x7F800000u;
    } else {
      int u = t - 128;
      sqc[u] = sqB[colBase + u]; tc[u] = tgtP[colBase + u];
      pmLc[u] = 0u; nmLc[u] = 0x7F800000u;
    }

    const unsigned short* Ag = Xb + (size_t)rowBase * D;
    const unsigned short* Bg = Xb + (size_t)colBase * D;

    int goff[2], lbase[2];
#pragma unroll
    for (int it = 0; it < 2; ++it) {
      int p = t + it * 256;
      int row = p >> 2;
      int c = (p & 3) ^ (row & 3);
      goff[it] = row * D + c * 8;
      lbase[it] = (it * 256 + wave * 64) * 16;
    }
    int aAddr[4], bAddr[4];
#pragma unroll
    for (int mi = 0; mi < 4; ++mi) {
      int row = wy * 64 + mi * 16 + l15;
      aAddr[mi] = (row * 4 + (quad ^ (row & 3))) * 16;
    }
#pragma unroll
    for (int nj = 0; nj < 4; ++nj) {
      int col = wx * 64 + nj * 16 + l15;
      bAddr[nj] = (col * 4 + (quad ^ (col & 3))) * 16;
    }

    STAGE(0, 0);

    floatx4 acc[4][4];
#pragma unroll
    for (int mi = 0; mi < 4; ++mi)
#pragma unroll
      for (int nj = 0; nj < 4; ++nj)
        acc[mi][nj] = (floatx4){0.f, 0.f, 0.f, 0.f};

#pragma unroll
    for (int m = 0; m < 4; ++m) {
      __syncthreads();
      if (m < 3) STAGE(m + 1, (m + 1) & 1);
#pragma unroll
      for (int s = 0; s < 2; ++s) {
        const char* ab = (const char*)As + ((m & 1) * 2 + s) * 8192;
        const char* bb = (const char*)Bs + ((m & 1) * 2 + s) * 8192;
        bf16x8 a[4], b[4];
#pragma unroll
        for (int mi = 0; mi < 4; ++mi)
          a[mi] = *reinterpret_cast<const bf16x8*>(ab + aAddr[mi]);
#pragma unroll
        for (int nj = 0; nj < 4; ++nj)
          b[nj] = *reinterpret_cast<const bf16x8*>(bb + bAddr[nj]);
#pragma unroll
        for (int mi = 0; mi < 4; ++mi)
#pragma unroll
          for (int nj = 0; nj < 4; ++nj)
            acc[mi][nj] = __builtin_amdgcn_mfma_f32_16x16x32_bf16(a[mi], b[nj], acc[mi][nj], 0, 0, 0);
      }
    }

    // masked epilogue in key space
    float sqcB_l[4]; int tc_l[4];
#pragma unroll
    for (int nj = 0; nj < 4; ++nj) {
      int jl = wx * 64 + nj * 16 + l15;
      sqcB_l[nj] = sqc[jl];
      tc_l[nj]   = tc[jl];
    }

    float pm[16], nm[16], cmP[4], cmN[4];
#pragma unroll
    for (int s = 0; s < 16; ++s) { pm[s] = 0.f; nm[s] = __builtin_huge_valf(); }
#pragma unroll
    for (int nj = 0; nj < 4; ++nj) { cmP[nj] = 0.f; cmN[nj] = __builtin_huge_valf(); }

#pragma unroll
    for (int mi = 0; mi < 4; ++mi) {
#pragma unroll
      for (int r = 0; r < 4; ++r) {
        int il = wy * 64 + mi * 16 + quad * 4 + r;
        float siB = sqr[il];
        int   ti  = tr[il];
        int   s   = mi * 4 + r;
#pragma unroll
        for (int nj = 0; nj < 4; ++nj) {
          float dot = acc[mi][nj][r];
          float rk = fmaf(-2.f, dot, sqcB_l[nj]);
          float ck = fmaf(-2.f, dot, siB);
          bool same = (ti == tc_l[nj]);
          pm[s]   = fmaxf(pm[s],   same ? rk : 0.f);
          nm[s]   = fminf(nm[s],   same ? __builtin_huge_valf() : rk);
          cmP[nj] = fmaxf(cmP[nj], same ? ck : 0.f);
          cmN[nj] = fminf(cmN[nj], same ? __builtin_huge_valf() : ck);
        }
      }
    }

#pragma unroll
    for (int m = 8; m >= 1; m >>= 1) {
#pragma unroll
      for (int j = 0; j < m; ++j) {
        bool up = (l15 & m) != 0;
        float sp = up ? pm[j] : pm[j + m];
        float sn = up ? nm[j] : nm[j + m];
        float rp = __shfl_xor(sp, m);
        float rn = __shfl_xor(sn, m);
        float kp = up ? pm[j + m] : pm[j];
        float kn = up ? nm[j + m] : nm[j];
        pm[j] = fmaxf(kp, rp);
        nm[j] = fminf(kn, rn);
      }
    }
    {
      int rowIdx = wy * 64 + ((l15 >> 2) << 4) + (quad << 2) + (l15 & 3);
      atomicMax(&pmL[rowIdx], __float_as_uint(pm[0]));
      atomicMin(&nmL[rowIdx], __float_as_uint(nm[0]));
    }
#pragma unroll
    for (int nj = 0; nj < 4; ++nj) {
      cmP[nj] = fmaxf(cmP[nj], __shfl_xor(cmP[nj], 16));
      cmP[nj] = fmaxf(cmP[nj], __shfl_xor(cmP[nj], 32));
      cmN[nj] = fminf(cmN[nj], __shfl_xor(cmN[nj], 16));
      cmN[nj] = fminf(cmN[nj], __shfl_xor(cmN[nj], 32));
    }
    {
      float vP = (quad == 0) ? cmP[0] : (quad == 1) ? cmP[1] : (quad == 2) ? cmP[2] : cmP[3];
      float vN = (quad == 0) ? cmN[0] : (quad == 1) ? cmN[1] : (quad == 2) ? cmN[2] : cmN[3];
      int colIdx = wx * 64 + quad * 16 + l15;
      atomicMax(&pmLc[colIdx], __float_as_uint(vP));
      atomicMin(&nmLc[colIdx], __float_as_uint(vN));
    }
    __syncthreads();

    if (t < 128) {
      atomicMax(&pmax[rowBase + t], pmL[t]);
      atomicMin(&nmin[rowBase + t], nmL[t]);
    } else {
      int u = t - 128;
      atomicMax(&pmax[colBase + u], pmLc[u]);
      atomicMin(&nmin[colBase + u], nmLc[u]);
    }
  }

  // ---- arrival counter + last-block finish (NO fence; see header) ----
  __syncthreads();  // drains each wave's global atomics (vmcnt) before ticket
  if (t == 0) ticketS = atomicAdd(counter, 1u);
  __syncthreads();
  if (ticketS == NBLK - 1) {
    float lsum = 0.f, psum = 0.f;
    for (int i = t; i < N; i += 256) {
      // device-scope no-op atomics as coherent reads (XCD-safe)
      float pmv = __uint_as_float(atomicMax(&pmax[i], 0u));
      float nmv = __uint_as_float(atomicMin(&nmin[i], 0xFFFFFFFFu));
      float sq2 = sqB[i] - 2.0f * BIAS;  // s_i - B
      float ap = sqrtf(fmaxf(sq2 + pmv, 1e-12f));
      float an = sqrtf(fmaxf(sq2 + nmv, 1e-12f));
      lsum += fmaxf(ap - an + MARGIN, 0.f);
      psum += (an > ap) ? 1.f : 0.f;
    }
#pragma unroll
    for (int o = 32; o > 0; o >>= 1) {
      lsum += __shfl_down(lsum, o);
      psum += __shfl_down(psum, o);
    }
    if (lane == 0) { ls[wave] = lsum; ps[wave] = psum; }
    __syncthreads();
    if (t == 0) {
      out[0] = (ls[0] + ls[1] + ls[2] + ls[3]) * (1.0f / (float)N);
      out[1] = (ps[0] + ps[1] + ps[2] + ps[3]) * (1.0f / (float)N);
    }
  }
}

extern "C" void kernel_launch(void* const* d_in, const int* in_sizes, int n_in,
                              void* d_out, int out_size, void* d_ws, size_t ws_size,
                              hipStream_t stream) {
  const float* X  = (const float*)d_in[0];
  const int* tgt  = (const int*)d_in[1];
  float* out      = (float*)d_out;

  char* ws = (char*)d_ws;
  unsigned short* Xb = (unsigned short*)ws;                    // 4 MiB (sorted)
  float*    sqB   = (float*)(ws + 4194304);                    // 32 KiB (s_i + B)
  int*      tgtP  = (int*)(ws + 4194304 + 32768);              // 32 KiB (sorted cls)
  unsigned* pmax  = (unsigned*)(ws + 4194304 + 65536);         // 32 KiB
  unsigned* nmin  = (unsigned*)(ws + 4194304 + 98304);         // 32 KiB
  unsigned* cnt   = (unsigned*)(ws + 4194304 + 131072);        // 4 B

  prep_kernel<<<1024, 256, 0, stream>>>(X, tgt, Xb, sqB, tgtP, pmax, nmin, cnt);
  tile_fast<<<NBLK, 256, 0, stream>>>(Xb, sqB, tgtP, nmin);
  tile_slow<<<NBLK, 256, 0, stream>>>(Xb, sqB, tgtP, pmax, nmin, cnt, out);
}

// Round 10
// 129.838 us; speedup vs baseline: 1.1706x; 1.1706x over previous
//
#include <hip/hip_runtime.h>
#include <hip/hip_bf16.h>

// TripletLoss, N=8192, D=256 fp32, targets in [0,128).
// out[0]=mean(relu(dist_ap-dist_an+0.3)), out[1]=mean(dist_an>dist_ap)
// dist=sqrt(clip(si+sj-2dot,1e-12)); clip/sqrt deferred (monotone).
// Reductions in KEY SPACE: key = B + s_other - 2dot (B=65536 keeps keys
// positive -> uint order == float order for atomicMax/Min).
//
// Ledger: R5: never __threadfence per block (buffer_wbl2+inv wipes XCD L2, 3x).
// R7: waves/SIMD = 512/(VGPR+AGPR); keep fast path in its own kernel.
// R8: BK=64 regressed twice over (occupancy + 2080-block LDS drain in the
// sparse slow kernel); fused-finish ticket also regressed. Both reverted.
// R9: (1) tile_slow PERSISTENT: 256 blocks grid-stride over 2080 tile ids,
// only ~127 active -> no dead-block LDS drain. (2) tile_fast
// __launch_bounds__(256,4): cap regs at 128 unified -> 4 blocks/CU.

#define N 8192
#define D 256
#define MARGIN 0.3f
#define NBLK 2080   // 64*65/2 lower-triangle 128x128 tiles
#define BIAS 65536.0f

typedef __bf16  bf16x8  __attribute__((ext_vector_type(8)));
typedef float   floatx4 __attribute__((ext_vector_type(4)));

__device__ __forceinline__ void load_lds16(const void* g, void* s) {
  __builtin_amdgcn_global_load_lds(
      (const __attribute__((address_space(1))) void*)g,
      (__attribute__((address_space(3))) void*)s, 16, 0, 0);
}

__device__ __forceinline__ void tri_decode(int bi, int& by, int& bx) {
  by = (int)((sqrtf(8.0f * (float)bi + 1.0f) - 1.0f) * 0.5f);
  while ((by + 1) * (by + 2) / 2 <= bi) ++by;
  while (by * (by + 1) / 2 > bi) --by;
  bx = bi - by * (by + 1) / 2;
}

// ---- Kernel A: rank-sort by class + bf16 cast + biased sq-norms + init ------
__global__ __launch_bounds__(256) void prep_kernel(
    const float* __restrict__ X, const int* __restrict__ tgt,
    unsigned short* __restrict__ Xb, float* __restrict__ sqB,
    int* __restrict__ tgtP, unsigned* __restrict__ pmax, unsigned* __restrict__ nmin) {
  __shared__ int keys[N];  // 32 KB: key = cls*16384 + j (lexicographic rank)
  const int t = threadIdx.x;
  const int lane = t & 63, wave = t >> 6;
#pragma unroll
  for (int u = 0; u < 32; ++u) {
    int j = u * 256 + t;
    keys[j] = tgt[j] * 16384 + j;
  }
  __syncthreads();
  const int row0 = blockIdx.x * 8 + wave * 2;
#pragma unroll
  for (int r = 0; r < 2; ++r) {
    const int row = row0 + r;
    const int Ki = keys[row];
    int cnt = 0;
#pragma unroll 4
    for (int u = 0; u < 32; ++u) {
      int4 k4 = *reinterpret_cast<const int4*>(&keys[u * 256 + lane * 4]);
      cnt += (k4.x < Ki) + (k4.y < Ki) + (k4.z < Ki) + (k4.w < Ki);
    }
#pragma unroll
    for (int o = 1; o < 64; o <<= 1) cnt += __shfl_xor(cnt, o);
    // cnt == sorted position (uniform across lanes)
    float4 v = *reinterpret_cast<const float4*>(X + (size_t)row * D + lane * 4);
    ushort4 h;
    {
      __hip_bfloat16 b0 = __float2bfloat16(v.x), b1 = __float2bfloat16(v.y);
      __hip_bfloat16 b2 = __float2bfloat16(v.z), b3 = __float2bfloat16(v.w);
      h.x = *reinterpret_cast<unsigned short*>(&b0);
      h.y = *reinterpret_cast<unsigned short*>(&b1);
      h.z = *reinterpret_cast<unsigned short*>(&b2);
      h.w = *reinterpret_cast<unsigned short*>(&b3);
    }
    *reinterpret_cast<ushort4*>(Xb + (size_t)cnt * D + lane * 4) = h;
    float s = v.x * v.x + v.y * v.y + v.z * v.z + v.w * v.w;
#pragma unroll
    for (int o = 32; o > 0; o >>= 1) s += __shfl_down(s, o);
    if (lane == 0) {
      sqB[cnt]  = s + BIAS;
      tgtP[cnt] = Ki >> 14;
      pmax[row] = 0u;            // identity for max of positive keys
      nmin[row] = 0x7F800000u;   // +inf
    }
  }
}

// ---- Kernel B1: FAST tiles (no same-class pairs) — maskless min only --------
__global__ __launch_bounds__(256, 4) void tile_fast(
    const unsigned short* __restrict__ Xb, const float* __restrict__ sqB,
    const int* __restrict__ tgtP, unsigned* __restrict__ nmin) {
  int by, bx; tri_decode(blockIdx.x, by, bx);
  const int rowBase = by * 128, colBase = bx * 128;
  if (tgtP[rowBase + 127] >= tgtP[colBase] && tgtP[colBase + 127] >= tgtP[rowBase])
    return;  // overlap -> slow kernel

  const int t = threadIdx.x;
  const int lane = t & 63, wave = t >> 6;
  const int wy = wave >> 1, wx = wave & 1;
  const int quad = lane >> 4, l15 = lane & 15;

  // XOR-swizzled tiles (chunk p holds global chunk (row=p>>2, c=(p&3)^(row&3)))
  __shared__ __align__(16) unsigned short As[2][128 * 32];  // 8 KB x2
  __shared__ __align__(16) unsigned short Bs[2][128 * 32];  // 8 KB x2
  __shared__ float sqr[128], sqc[128];
  __shared__ unsigned nmL[128], nmLc[128];

  if (t < 128) { sqr[t] = sqB[rowBase + t]; nmL[t] = 0x7F800000u; }
  else { int u = t - 128; sqc[u] = sqB[colBase + u]; nmLc[u] = 0x7F800000u; }

  const unsigned short* Ag = Xb + (size_t)rowBase * D;
  const unsigned short* Bg = Xb + (size_t)colBase * D;

  int goff[2], lbase[2];
#pragma unroll
  for (int it = 0; it < 2; ++it) {
    int p = t + it * 256;
    int row = p >> 2;
    int c = (p & 3) ^ (row & 3);
    goff[it] = row * D + c * 8;
    lbase[it] = (it * 256 + wave * 64) * 16;
  }
  int aAddr[4], bAddr[4];
#pragma unroll
  for (int mi = 0; mi < 4; ++mi) {
    int row = wy * 64 + mi * 16 + l15;
    aAddr[mi] = (row * 4 + (quad ^ (row & 3))) * 16;
  }
#pragma unroll
  for (int nj = 0; nj < 4; ++nj) {
    int col = wx * 64 + nj * 16 + l15;
    bAddr[nj] = (col * 4 + (quad ^ (col & 3))) * 16;
  }

#pragma unroll
  for (int it = 0; it < 2; ++it) {
    load_lds16(Ag + goff[it], (char*)As[0] + lbase[it]);
    load_lds16(Bg + goff[it], (char*)Bs[0] + lbase[it]);
  }

  floatx4 acc[4][4];
#pragma unroll
  for (int mi = 0; mi < 4; ++mi)
#pragma unroll
    for (int nj = 0; nj < 4; ++nj)
      acc[mi][nj] = (floatx4){0.f, 0.f, 0.f, 0.f};

  for (int kk = 0; kk < 8; ++kk) {
    __syncthreads();  // drains buf[kk]'s DMA (issued one compute phase ago)
    if (kk < 7) {
      int k0n = (kk + 1) * 32;
      char* an = (char*)As[(kk + 1) & 1];
      char* bn = (char*)Bs[(kk + 1) & 1];
#pragma unroll
      for (int it = 0; it < 2; ++it) {
        load_lds16(Ag + goff[it] + k0n, an + lbase[it]);
        load_lds16(Bg + goff[it] + k0n, bn + lbase[it]);
      }
    }
    const char* abuf = (const char*)As[kk & 1];
    const char* bbuf = (const char*)Bs[kk & 1];
    bf16x8 a[4], b[4];
#pragma unroll
    for (int mi = 0; mi < 4; ++mi)
      a[mi] = *reinterpret_cast<const bf16x8*>(abuf + aAddr[mi]);
#pragma unroll
    for (int nj = 0; nj < 4; ++nj)
      b[nj] = *reinterpret_cast<const bf16x8*>(bbuf + bAddr[nj]);
#pragma unroll
    for (int mi = 0; mi < 4; ++mi)
#pragma unroll
      for (int nj = 0; nj < 4; ++nj)
        acc[mi][nj] = __builtin_amdgcn_mfma_f32_16x16x32_bf16(a[mi], b[nj], acc[mi][nj], 0, 0, 0);
  }

  // maskless epilogue: rowkey = sqB_col - 2dot (-> nmL), colkey = sqB_row - 2dot
  float sqcB_l[4];
#pragma unroll
  for (int nj = 0; nj < 4; ++nj) sqcB_l[nj] = sqc[wx * 64 + nj * 16 + l15];

  float nm[16], cmN[4];
#pragma unroll
  for (int s = 0; s < 16; ++s) nm[s] = __builtin_huge_valf();
#pragma unroll
  for (int nj = 0; nj < 4; ++nj) cmN[nj] = __builtin_huge_valf();

#pragma unroll
  for (int mi = 0; mi < 4; ++mi) {
    floatx4 siB4 = *reinterpret_cast<const floatx4*>(&sqr[wy * 64 + mi * 16 + quad * 4]);
#pragma unroll
    for (int r = 0; r < 4; ++r) {
      float siB = siB4[r];
      int s = mi * 4 + r;
#pragma unroll
      for (int nj = 0; nj < 4; ++nj) {
        float dot = acc[mi][nj][r];
        nm[s]   = fminf(nm[s],   fmaf(-2.f, dot, sqcB_l[nj]));
        cmN[nj] = fminf(cmN[nj], fmaf(-2.f, dot, siB));
      }
    }
  }

#pragma unroll
  for (int m = 8; m >= 1; m >>= 1) {
#pragma unroll
    for (int j = 0; j < m; ++j) {
      bool up = (l15 & m) != 0;
      float sn = up ? nm[j] : nm[j + m];
      float rn = __shfl_xor(sn, m);
      float kn = up ? nm[j + m] : nm[j];
      nm[j] = fminf(kn, rn);
    }
  }
  {
    int rowIdx = wy * 64 + ((l15 >> 2) << 4) + (quad << 2) + (l15 & 3);
    atomicMin(&nmL[rowIdx], __float_as_uint(nm[0]));
  }
#pragma unroll
  for (int nj = 0; nj < 4; ++nj) {
    cmN[nj] = fminf(cmN[nj], __shfl_xor(cmN[nj], 16));
    cmN[nj] = fminf(cmN[nj], __shfl_xor(cmN[nj], 32));
  }
  {
    float vN = (quad == 0) ? cmN[0] : (quad == 1) ? cmN[1] : (quad == 2) ? cmN[2] : cmN[3];
    atomicMin(&nmLc[wx * 64 + quad * 16 + l15], __float_as_uint(vN));
  }
  __syncthreads();

  if (t < 128) atomicMin(&nmin[rowBase + t], nmL[t]);
  else { int u = t - 128; atomicMin(&nmin[colBase + u], nmLc[u]); }
}

// ---- Kernel B2: SLOW tiles, PERSISTENT (256 blocks grid-stride 2080 ids) ----
__global__ __launch_bounds__(256) void tile_slow(
    const unsigned short* __restrict__ Xb, const float* __restrict__ sqB,
    const int* __restrict__ tgtP, unsigned* __restrict__ pmax, unsigned* __restrict__ nmin) {
  const int t = threadIdx.x;
  const int lane = t & 63, wave = t >> 6;
  const int wy = wave >> 1, wx = wave & 1;
  const int quad = lane >> 4, l15 = lane & 15;

  __shared__ __align__(16) unsigned short As[2][128 * 32];
  __shared__ __align__(16) unsigned short Bs[2][128 * 32];
  __shared__ float sqr[128], sqc[128];
  __shared__ int   tr[128], tc[128];
  __shared__ unsigned pmL[128], nmL[128], pmLc[128], nmLc[128];

  // tile-invariant per-thread addressing
  int goff[2], lbase[2];
#pragma unroll
  for (int it = 0; it < 2; ++it) {
    int p = t + it * 256;
    int row = p >> 2;
    int c = (p & 3) ^ (row & 3);
    goff[it] = row * D + c * 8;
    lbase[it] = (it * 256 + wave * 64) * 16;
  }
  int aAddr[4], bAddr[4];
#pragma unroll
  for (int mi = 0; mi < 4; ++mi) {
    int row = wy * 64 + mi * 16 + l15;
    aAddr[mi] = (row * 4 + (quad ^ (row & 3))) * 16;
  }
#pragma unroll
  for (int nj = 0; nj < 4; ++nj) {
    int col = wx * 64 + nj * 16 + l15;
    bAddr[nj] = (col * 4 + (quad ^ (col & 3))) * 16;
  }

  for (int bi = blockIdx.x; bi < NBLK; bi += gridDim.x) {
    int by, bx; tri_decode(bi, by, bx);
    const int rowBase = by * 128, colBase = bx * 128;
    // block-uniform overlap test (scalar loads) -> skip non-overlap tiles
    if (!(tgtP[rowBase + 127] >= tgtP[colBase] && tgtP[colBase + 127] >= tgtP[rowBase]))
      continue;

    __syncthreads();  // guard LDS reuse against previous tile's merge reads
    if (t < 128) {
      sqr[t] = sqB[rowBase + t]; tr[t] = tgtP[rowBase + t];
      pmL[t] = 0u; nmL[t] = 0x7F800000u;
    } else {
      int u = t - 128;
      sqc[u] = sqB[colBase + u]; tc[u] = tgtP[colBase + u];
      pmLc[u] = 0u; nmLc[u] = 0x7F800000u;
    }

    const unsigned short* Ag = Xb + (size_t)rowBase * D;
    const unsigned short* Bg = Xb + (size_t)colBase * D;

#pragma unroll
    for (int it = 0; it < 2; ++it) {
      load_lds16(Ag + goff[it], (char*)As[0] + lbase[it]);
      load_lds16(Bg + goff[it], (char*)Bs[0] + lbase[it]);
    }

    floatx4 acc[4][4];
#pragma unroll
    for (int mi = 0; mi < 4; ++mi)
#pragma unroll
      for (int nj = 0; nj < 4; ++nj)
        acc[mi][nj] = (floatx4){0.f, 0.f, 0.f, 0.f};

    for (int kk = 0; kk < 8; ++kk) {
      __syncthreads();
      if (kk < 7) {
        int k0n = (kk + 1) * 32;
        char* an = (char*)As[(kk + 1) & 1];
        char* bn = (char*)Bs[(kk + 1) & 1];
#pragma unroll
        for (int it = 0; it < 2; ++it) {
          load_lds16(Ag + goff[it] + k0n, an + lbase[it]);
          load_lds16(Bg + goff[it] + k0n, bn + lbase[it]);
        }
      }
      const char* abuf = (const char*)As[kk & 1];
      const char* bbuf = (const char*)Bs[kk & 1];
      bf16x8 a[4], b[4];
#pragma unroll
      for (int mi = 0; mi < 4; ++mi)
        a[mi] = *reinterpret_cast<const bf16x8*>(abuf + aAddr[mi]);
#pragma unroll
      for (int nj = 0; nj < 4; ++nj)
        b[nj] = *reinterpret_cast<const bf16x8*>(bbuf + bAddr[nj]);
#pragma unroll
      for (int mi = 0; mi < 4; ++mi)
#pragma unroll
        for (int nj = 0; nj < 4; ++nj)
          acc[mi][nj] = __builtin_amdgcn_mfma_f32_16x16x32_bf16(a[mi], b[nj], acc[mi][nj], 0, 0, 0);
    }

    // masked epilogue in key space
    float sqcB_l[4]; int tc_l[4];
#pragma unroll
    for (int nj = 0; nj < 4; ++nj) {
      int jl = wx * 64 + nj * 16 + l15;
      sqcB_l[nj] = sqc[jl];
      tc_l[nj]   = tc[jl];
    }

    float pm[16], nm[16], cmP[4], cmN[4];
#pragma unroll
    for (int s = 0; s < 16; ++s) { pm[s] = 0.f; nm[s] = __builtin_huge_valf(); }
#pragma unroll
    for (int nj = 0; nj < 4; ++nj) { cmP[nj] = 0.f; cmN[nj] = __builtin_huge_valf(); }

#pragma unroll
    for (int mi = 0; mi < 4; ++mi) {
#pragma unroll
      for (int r = 0; r < 4; ++r) {
        int il = wy * 64 + mi * 16 + quad * 4 + r;
        float siB = sqr[il];
        int   ti  = tr[il];
        int   s   = mi * 4 + r;
#pragma unroll
        for (int nj = 0; nj < 4; ++nj) {
          float dot = acc[mi][nj][r];
          float rk = fmaf(-2.f, dot, sqcB_l[nj]);
          float ck = fmaf(-2.f, dot, siB);
          bool same = (ti == tc_l[nj]);
          pm[s]   = fmaxf(pm[s],   same ? rk : 0.f);
          nm[s]   = fminf(nm[s],   same ? __builtin_huge_valf() : rk);
          cmP[nj] = fmaxf(cmP[nj], same ? ck : 0.f);
          cmN[nj] = fminf(cmN[nj], same ? __builtin_huge_valf() : ck);
        }
      }
    }

#pragma unroll
    for (int m = 8; m >= 1; m >>= 1) {
#pragma unroll
      for (int j = 0; j < m; ++j) {
        bool up = (l15 & m) != 0;
        float sp = up ? pm[j] : pm[j + m];
        float sn = up ? nm[j] : nm[j + m];
        float rp = __shfl_xor(sp, m);
        float rn = __shfl_xor(sn, m);
        float kp = up ? pm[j + m] : pm[j];
        float kn = up ? nm[j + m] : nm[j];
        pm[j] = fmaxf(kp, rp);
        nm[j] = fminf(kn, rn);
      }
    }
    {
      int rowIdx = wy * 64 + ((l15 >> 2) << 4) + (quad << 2) + (l15 & 3);
      atomicMax(&pmL[rowIdx], __float_as_uint(pm[0]));
      atomicMin(&nmL[rowIdx], __float_as_uint(nm[0]));
    }
#pragma unroll
    for (int nj = 0; nj < 4; ++nj) {
      cmP[nj] = fmaxf(cmP[nj], __shfl_xor(cmP[nj], 16));
      cmP[nj] = fmaxf(cmP[nj], __shfl_xor(cmP[nj], 32));
      cmN[nj] = fminf(cmN[nj], __shfl_xor(cmN[nj], 16));
      cmN[nj] = fminf(cmN[nj], __shfl_xor(cmN[nj], 32));
    }
    {
      float vP = (quad == 0) ? cmP[0] : (quad == 1) ? cmP[1] : (quad == 2) ? cmP[2] : cmP[3];
      float vN = (quad == 0) ? cmN[0] : (quad == 1) ? cmN[1] : (quad == 2) ? cmN[2] : cmN[3];
      int colIdx = wx * 64 + quad * 16 + l15;
      atomicMax(&pmLc[colIdx], __float_as_uint(vP));
      atomicMin(&nmLc[colIdx], __float_as_uint(vN));
    }
    __syncthreads();

    if (t < 128) {
      atomicMax(&pmax[rowBase + t], pmL[t]);
      atomicMin(&nmin[rowBase + t], nmL[t]);
    } else {
      int u = t - 128;
      atomicMax(&pmax[colBase + u], pmLc[u]);
      atomicMin(&nmin[colBase + u], nmLc[u]);
    }
  }
}

// ---- Kernel C: final loss/prec (1 block) ------------------------------------
__global__ __launch_bounds__(256) void finish_kernel(
    const unsigned* __restrict__ pmax, const unsigned* __restrict__ nmin,
    const float* __restrict__ sqB, float* __restrict__ out) {
  const int t = threadIdx.x;
  float lsum = 0.f, psum = 0.f;
  for (int i = t; i < N; i += 256) {
    float sq2 = sqB[i] - 2.0f * BIAS;  // s_i - B
    float ap2 = sq2 + __uint_as_float(pmax[i]);
    float an2 = sq2 + __uint_as_float(nmin[i]);
    float ap = sqrtf(fmaxf(ap2, 1e-12f));
    float an = sqrtf(fmaxf(an2, 1e-12f));
    lsum += fmaxf(ap - an + MARGIN, 0.f);
    psum += (an > ap) ? 1.f : 0.f;
  }
#pragma unroll
  for (int o = 32; o > 0; o >>= 1) {
    lsum += __shfl_down(lsum, o);
    psum += __shfl_down(psum, o);
  }
  __shared__ float ls[4], ps[4];
  if ((t & 63) == 0) { ls[t >> 6] = lsum; ps[t >> 6] = psum; }
  __syncthreads();
  if (t == 0) {
    out[0] = (ls[0] + ls[1] + ls[2] + ls[3]) * (1.0f / (float)N);
    out[1] = (ps[0] + ps[1] + ps[2] + ps[3]) * (1.0f / (float)N);
  }
}

extern "C" void kernel_launch(void* const* d_in, const int* in_sizes, int n_in,
                              void* d_out, int out_size, void* d_ws, size_t ws_size,
                              hipStream_t stream) {
  const float* X  = (const float*)d_in[0];
  const int* tgt  = (const int*)d_in[1];
  float* out      = (float*)d_out;

  char* ws = (char*)d_ws;
  unsigned short* Xb = (unsigned short*)ws;                    // 4 MiB (sorted)
  float*    sqB   = (float*)(ws + 4194304);                    // 32 KiB (s_i + B)
  int*      tgtP  = (int*)(ws + 4194304 + 32768);              // 32 KiB (sorted cls)
  unsigned* pmax  = (unsigned*)(ws + 4194304 + 65536);         // 32 KiB
  unsigned* nmin  = (unsigned*)(ws + 4194304 + 98304);         // 32 KiB

  prep_kernel<<<1024, 256, 0, stream>>>(X, tgt, Xb, sqB, tgtP, pmax, nmin);
  tile_fast<<<NBLK, 256, 0, stream>>>(Xb, sqB, tgtP, nmin);
  tile_slow<<<256, 256, 0, stream>>>(Xb, sqB, tgtP, pmax, nmin);
  finish_kernel<<<1, 256, 0, stream>>>(pmax, nmin, sqB, out);
}